// Round 8
// baseline (282.273 us; speedup 1.0000x reference)
//
#include <hip/hip_runtime.h>
#include <hip/hip_fp16.h>

#define DIMV 3
#define RV 3
#define CV 32
#define FV 64
#define ROWF 67
#define ROWO 35
#define CAP 64          // padded slots per node; Poisson(16) deg, huge margin
#define SCAN_T 1024

// 8-byte packed edge record: u0,u1,u2,hsum_dst as 4x fp16
struct __align__(8) U8 { __half2 xy; __half2 zw; };

__device__ __forceinline__ float fast_tanh(float x) {
    float ex = __expf(2.0f * x);
    return (ex - 1.0f) * __builtin_amdgcn_rcpf(ex + 1.0f);
}

// ---------- prep: nd[n]={x,y,z,hsum}; zero counts; out coords ----------
__global__ void prep_kernel(const float* __restrict__ features,
                            float4* __restrict__ nd,
                            int* __restrict__ counts,
                            float* __restrict__ out, int N) {
    int gid = blockIdx.x * blockDim.x + threadIdx.x;
    if (gid < N) counts[gid] = 0;
    int node = gid >> 6;
    int lane = threadIdx.x & 63;
    if (node >= N) return;
    const float* row = features + (size_t)node * ROWF;
    float f0 = row[lane];                                    // 0..63
    float f1 = (lane < ROWF - 64) ? row[64 + lane] : 0.0f;   // 64..66
    float v = (lane >= DIMV ? f0 : 0.0f) + f1;               // h = 3..66
    for (int off = 32; off > 0; off >>= 1) v += __shfl_xor(v, off, 64);
    float c0 = __shfl(f0, 0, 64);
    float c1 = __shfl(f0, 1, 64);
    float c2 = __shfl(f0, 2, 64);
    if (lane == 0) nd[node] = make_float4(c0, c1, c2, v);
    if (lane < DIMV) out[(size_t)node * ROWO + lane] = f0;
}

// ---------- primary: scatter packed u into per-src buckets ----------
__global__ void scatter_pad8_kernel(const int2* __restrict__ ei2,
                                    const float4* __restrict__ nd,
                                    const float* __restrict__ wd,
                                    const float* __restrict__ bd,
                                    int* __restrict__ counts,
                                    U8* __restrict__ ue_pad, int E) {
    int e = blockIdx.x * blockDim.x + threadIdx.x;
    if (e >= E) return;
    int2 sd = ei2[e];
    int k = atomicAdd(counts + sd.x, 1);
    if (k >= CAP) k = CAP - 1;   // OOB guard only; max deg ~40 expected
    float4 ps = nd[sd.x];
    float4 pd = nd[sd.y];
    float dx = pd.x - ps.x, dy = pd.y - ps.y, dz = pd.z - ps.z;
    // w_dense (DIM,R) row-major: u_j = dx*wd[j] + dy*wd[3+j] + dz*wd[6+j] + bd[j]
    float u0 = fast_tanh(dx * wd[0] + dy * wd[3] + dz * wd[6] + bd[0]);
    float u1 = fast_tanh(dx * wd[1] + dy * wd[4] + dz * wd[7] + bd[1]);
    float u2 = fast_tanh(dx * wd[2] + dy * wd[5] + dz * wd[8] + bd[2]);
    U8 r;
    r.xy = __floats2half2_rn(u0, u1);
    r.zw = __floats2half2_rn(u2, pd.w);
    ue_pad[(size_t)sd.x * CAP + k] = r;
}

// primary accumulate: 2 nodes per wave, lane=(c=lane&31, which=lane>>5).
// XCD-aware block swizzle: each XCD gets a contiguous node range so mu/sig
// lines are fetched by ONE per-XCD L2 instead of ~8.
// Buckets staged to LDS with one coalesced pass; compute loop reads LDS
// broadcast. No shuffle reduction (each lane owns its (node,c) fully).
__global__ void node_pad8_kernel(const int* __restrict__ counts,
                                 const U8* __restrict__ ue_pad,
                                 const float* __restrict__ mu,
                                 const float* __restrict__ sig,
                                 float* __restrict__ out, int N, int G, int chunk) {
    __shared__ U8 smq[4][2][CAP];
    int lb_raw = blockIdx.x;
    int lb = (lb_raw & 7) * chunk + (lb_raw >> 3);   // mixed-radix transpose
    bool bvalid = lb < G;
    int w = threadIdx.x >> 6;
    int lane = threadIdx.x & 63;
    int c = lane & 31;
    int which = lane >> 5;
    int nodeA = lb * 8 + w * 2;          // this wave's two nodes
    int node = nodeA + which;            // this lane's node
    bool valid = bvalid && node < N;

    float m0 = 0, m1 = 0, m2 = 0, i0 = 1, i1 = 1, i2 = 1;
    int cnt = 0;
    if (valid) {
        size_t slab = (size_t)N * RV;
        const float* mp = mu + (size_t)c * slab + (size_t)node * RV;
        const float* sp = sig + (size_t)c * slab + (size_t)node * RV;
        m0 = mp[0]; m1 = mp[1]; m2 = mp[2];
        i0 = __builtin_amdgcn_rcpf(sp[0]);
        i1 = __builtin_amdgcn_rcpf(sp[1]);
        i2 = __builtin_amdgcn_rcpf(sp[2]);
        cnt = counts[node];
        if (cnt > CAP) cnt = CAP;
    }
    // stage both nodes' buckets: lane covers slot index for A and B
    if (bvalid) {
        int nB = nodeA + 1;
        int cA = (nodeA < N) ? min(counts[nodeA], CAP) : 0;
        int cB = (nB < N) ? min(counts[nB], CAP) : 0;
        if (lane < cA) smq[w][0][lane] = ue_pad[(size_t)nodeA * CAP + lane];
        if (lane < cB) smq[w][1][lane] = ue_pad[(size_t)nB * CAP + lane];
    }
    __syncthreads();
    float acc = 0.0f;
    for (int k = 0; k < cnt; ++k) {
        U8 q = smq[w][which][k];
        float2 a = __half22float2(q.xy);
        float2 b = __half22float2(q.zw);
        float d0 = a.x - m0, d1 = a.y - m1, d2 = b.x - m2;
        float t = d0 * d0 * i0 + d1 * d1 * i1 + d2 * d2 * i2;
        acc += __expf(-0.5f * t) * b.y;
    }
    if (valid) out[(size_t)node * ROWO + DIMV + c] = acc;
}

// ---------- CSR fallback path (R6, fp32 records) ----------

__global__ void hist_kernel(const int2* __restrict__ ei2, int* __restrict__ counts, int E) {
    int e = blockIdx.x * blockDim.x + threadIdx.x;
    if (e >= E) return;
    atomicAdd(counts + ei2[e].x, 1);
}

__global__ void scan_a_kernel(const int* __restrict__ counts, int* __restrict__ offsets,
                              int* __restrict__ partials, int N) {
    __shared__ int sm[SCAN_T];
    int t = threadIdx.x;
    int i = blockIdx.x * SCAN_T + t;
    int c = (i < N) ? counts[i] : 0;
    sm[t] = c;
    __syncthreads();
    for (int off = 1; off < SCAN_T; off <<= 1) {
        int v = (t >= off) ? sm[t - off] : 0;
        __syncthreads();
        sm[t] += v;
        __syncthreads();
    }
    if (i < N) offsets[i] = sm[t] - c;
    if (t == SCAN_T - 1) partials[blockIdx.x] = sm[t];
}

__global__ void scan_b_kernel(int* __restrict__ partials, int B) {
    __shared__ int sm[SCAN_T];
    int t = threadIdx.x;
    int c = (t < B) ? partials[t] : 0;
    sm[t] = c;
    __syncthreads();
    for (int off = 1; off < SCAN_T; off <<= 1) {
        int v = (t >= off) ? sm[t - off] : 0;
        __syncthreads();
        sm[t] += v;
        __syncthreads();
    }
    if (t < B) partials[t] = sm[t] - c;
}

__global__ void scan_c_kernel(int* __restrict__ offsets, const int* __restrict__ partials,
                              int* __restrict__ cursor, int N, int E) {
    int i = blockIdx.x * blockDim.x + threadIdx.x;
    if (i == 0) offsets[N] = E;
    if (i >= N) return;
    int off = offsets[i] + partials[i / SCAN_T];
    offsets[i] = off;
    cursor[i] = off;
}

__global__ void scatter_u_kernel(const int2* __restrict__ ei2, int* __restrict__ cursor,
                                 const float4* __restrict__ nd,
                                 const float* __restrict__ wd, const float* __restrict__ bd,
                                 float4* __restrict__ ue, int E) {
    int e = blockIdx.x * blockDim.x + threadIdx.x;
    if (e >= E) return;
    int2 sd = ei2[e];
    int pos = atomicAdd(cursor + sd.x, 1);
    float4 ps = nd[sd.x];
    float4 pd = nd[sd.y];
    float dx = pd.x - ps.x, dy = pd.y - ps.y, dz = pd.z - ps.z;
    float u0 = fast_tanh(dx * wd[0] + dy * wd[3] + dz * wd[6] + bd[0]);
    float u1 = fast_tanh(dx * wd[1] + dy * wd[4] + dz * wd[7] + bd[1]);
    float u2 = fast_tanh(dx * wd[2] + dy * wd[5] + dz * wd[8] + bd[2]);
    ue[pos] = make_float4(u0, u1, u2, pd.w);
}

__global__ void node_acc2_kernel(const int* __restrict__ offsets,
                                 const float4* __restrict__ ue,
                                 const float* __restrict__ mu,
                                 const float* __restrict__ sig,
                                 float* __restrict__ out, int N) {
    int node = (blockIdx.x * blockDim.x + threadIdx.x) >> 6;
    if (node >= N) return;
    int lane = threadIdx.x & 63;
    int c = lane & 31;
    int half = lane >> 5;
    size_t slab = (size_t)N * RV;
    const float* mp = mu + (size_t)c * slab + (size_t)node * RV;
    const float* sp = sig + (size_t)c * slab + (size_t)node * RV;
    float m0 = mp[0], m1 = mp[1], m2 = mp[2];
    float i0 = __builtin_amdgcn_rcpf(sp[0]);
    float i1 = __builtin_amdgcn_rcpf(sp[1]);
    float i2 = __builtin_amdgcn_rcpf(sp[2]);
    int off0 = offsets[node], off1 = offsets[node + 1];
    float acc = 0.0f;
    for (int i = off0 + half; i < off1; i += 2) {
        float4 q = ue[i];
        float d0 = q.x - m0, d1 = q.y - m1, d2 = q.z - m2;
        float t = d0 * d0 * i0 + d1 * d1 * i1 + d2 * d2 * i2;
        acc += __expf(-0.5f * t) * q.w;
    }
    acc += __shfl_xor(acc, 32, 64);
    if (half == 0) out[(size_t)node * ROWO + DIMV + c] = acc;
}

// ---------- last-resort path (R4 edge-atomic) ----------

__global__ void fb_pre_kernel(const float* __restrict__ features,
                              float4* __restrict__ nd, float* __restrict__ out, int N) {
    int gid = blockIdx.x * blockDim.x + threadIdx.x;
    int node = gid >> 6;
    int lane = threadIdx.x & 63;
    if (node >= N) return;
    const float* row = features + (size_t)node * ROWF;
    float f0 = row[lane];
    float f1 = (lane < ROWF - 64) ? row[64 + lane] : 0.0f;
    float v = (lane >= DIMV ? f0 : 0.0f) + f1;
    for (int off = 32; off > 0; off >>= 1) v += __shfl_xor(v, off, 64);
    float c0 = __shfl(f0, 0, 64);
    float c1 = __shfl(f0, 1, 64);
    float c2 = __shfl(f0, 2, 64);
    if (lane == 0) nd[node] = make_float4(c0, c1, c2, v);
    float* orow = out + (size_t)node * ROWO;
    if (lane < DIMV) orow[lane] = f0;
    else if (lane < ROWO) orow[lane] = 0.0f;
}

__global__ void fb_edge_kernel(const int* __restrict__ ei, const float4* __restrict__ nd,
                               const float* __restrict__ wd, const float* __restrict__ bd,
                               const float* __restrict__ mu, const float* __restrict__ sig,
                               float* __restrict__ out, int N, int E) {
    int e = blockIdx.x * blockDim.x + threadIdx.x;
    if (e >= E) return;
    int s = ei[2 * e];
    int d = ei[2 * e + 1];
    float4 ps = nd[s];
    float4 pd = nd[d];
    float dx = pd.x - ps.x, dy = pd.y - ps.y, dz = pd.z - ps.z;
    float u0 = fast_tanh(dx * wd[0] + dy * wd[3] + dz * wd[6] + bd[0]);
    float u1 = fast_tanh(dx * wd[1] + dy * wd[4] + dz * wd[7] + bd[1]);
    float u2 = fast_tanh(dx * wd[2] + dy * wd[5] + dz * wd[8] + bd[2]);
    float hs = pd.w;
    float* oagg = out + (size_t)s * ROWO + DIMV;
    size_t nodeoff = (size_t)s * RV;
    size_t slab = (size_t)N * RV;
#pragma unroll 4
    for (int c = 0; c < CV; ++c) {
        const float* mp = mu + (size_t)c * slab + nodeoff;
        const float* sp = sig + (size_t)c * slab + nodeoff;
        float d0 = u0 - mp[0], d1 = u1 - mp[1], d2 = u2 - mp[2];
        float t = d0 * d0 * __builtin_amdgcn_rcpf(sp[0])
                + d1 * d1 * __builtin_amdgcn_rcpf(sp[1])
                + d2 * d2 * __builtin_amdgcn_rcpf(sp[2]);
        atomicAdd(oagg + c, __expf(-0.5f * t) * hs);
    }
}

extern "C" void kernel_launch(void* const* d_in, const int* in_sizes, int n_in,
                              void* d_out, int out_size, void* d_ws, size_t ws_size,
                              hipStream_t stream) {
    const float* features = (const float*)d_in[0];
    const int*   ei       = (const int*)d_in[1];
    const int2*  ei2      = (const int2*)d_in[1];
    const float* wd       = (const float*)d_in[2];
    const float* bd       = (const float*)d_in[3];
    const float* mu       = (const float*)d_in[4];
    const float* sig      = (const float*)d_in[5];
    float* out = (float*)d_out;

    int N = in_sizes[0] / ROWF;
    int E = in_sizes[1] / 2;
    int B = (N + SCAN_T - 1) / SCAN_T;

    size_t cur = 0;
    auto take = [&](size_t bytes) { size_t p = cur; cur += (bytes + 255) & ~(size_t)255; return p; };
    size_t o_nd      = take((size_t)N * sizeof(float4));
    size_t o_counts  = take((size_t)N * sizeof(int));
    size_t o_offsets = take((size_t)(N + 1) * sizeof(int));
    size_t o_cursor  = take((size_t)N * sizeof(int));
    size_t o_part    = take((size_t)SCAN_T * sizeof(int));
    size_t o_tail    = cur;     // ue_pad (packed) or ue (CSR fp32)
    size_t need_pad  = o_tail + (((size_t)N * CAP * sizeof(U8) + 255) & ~(size_t)255);
    size_t need_full = o_tail + (((size_t)E * sizeof(float4) + 255) & ~(size_t)255);

    char* ws = (char*)d_ws;
    float4* nd   = (float4*)(ws + o_nd);
    int* counts  = (int*)(ws + o_counts);
    int* offsets = (int*)(ws + o_offsets);
    int* cursor  = (int*)(ws + o_cursor);
    int* part    = (int*)(ws + o_part);

    if (ws_size >= need_pad) {
        U8* ue_pad = (U8*)(ws + o_tail);
        prep_kernel<<<(N + 3) / 4, 256, 0, stream>>>(features, nd, counts, out, N);
        scatter_pad8_kernel<<<(E + 255) / 256, 256, 0, stream>>>(ei2, nd, wd, bd, counts, ue_pad, E);
        int G = (N + 7) / 8;            // 8 nodes per block (4 waves x 2)
        int chunk = (G + 7) / 8;        // logical blocks per XCD
        node_pad8_kernel<<<chunk * 8, 256, 0, stream>>>(counts, ue_pad, mu, sig, out, N, G, chunk);
    } else if (ws_size >= need_full && B <= SCAN_T) {
        float4* ue = (float4*)(ws + o_tail);
        prep_kernel<<<(N + 3) / 4, 256, 0, stream>>>(features, nd, counts, out, N);
        hist_kernel<<<(E + 255) / 256, 256, 0, stream>>>(ei2, counts, E);
        scan_a_kernel<<<B, SCAN_T, 0, stream>>>(counts, offsets, part, N);
        scan_b_kernel<<<1, SCAN_T, 0, stream>>>(part, B);
        scan_c_kernel<<<(N + 255) / 256, 256, 0, stream>>>(offsets, part, cursor, N, E);
        scatter_u_kernel<<<(E + 255) / 256, 256, 0, stream>>>(ei2, cursor, nd, wd, bd, ue, E);
        node_acc2_kernel<<<(N + 3) / 4, 256, 0, stream>>>(offsets, ue, mu, sig, out, N);
    } else {
        fb_pre_kernel<<<(N + 3) / 4, 256, 0, stream>>>(features, nd, out, N);
        fb_edge_kernel<<<(E + 255) / 256, 256, 0, stream>>>(ei, nd, wd, bd, mu, sig, out, N, E);
    }
}